// Round 6
// baseline (195.981 us; speedup 1.0000x reference)
//
#include <hip/hip_runtime.h>
#include <math.h>

#define M_OBJ 4
#define N_PTS 3072
#define K_NN  10
#define NSLOT (M_OBJ - 1)
#define QPB   64            // queries per block (one per lane)
#define SEG   4             // reference segments (one per wave)
#define SEGN  (N_PTS / SEG) // 768 points per segment
#define B_CAND 40           // u16 candidate slots per lane
#define CSTR   41           // padded stride (odd -> bank spread)
#define PAD    16           // sref prefetch overrun pad

// T = inv(plane_T) @ est_T (3x4). plane_T is orthonormal-rigid: inv = [R^T|-R^T t].
__device__ inline void make_T(const float* __restrict__ E,
                              const float* __restrict__ P,
                              float T[3][4]) {
    float Pi[3][4];
#pragma unroll
    for (int i = 0; i < 3; ++i) {
#pragma unroll
        for (int j = 0; j < 3; ++j) Pi[i][j] = P[j * 4 + i];
        Pi[i][3] = -(P[0 * 4 + i] * P[3] + P[1 * 4 + i] * P[7] + P[2 * 4 + i] * P[11]);
    }
#pragma unroll
    for (int i = 0; i < 3; ++i) {
#pragma unroll
        for (int j = 0; j < 4; ++j) {
            float acc = (j == 3) ? Pi[i][3] : 0.0f;
#pragma unroll
            for (int kk = 0; kk < 3; ++kk) acc += Pi[i][kk] * E[kk * 4 + j];
            T[i][j] = acc;
        }
    }
}

// bs[] ASCENDING in s (s = p.q - |p|^2/2; larger s == nearer).
// bs[0] = 10th-best (threshold), bs[9] = nearest. Compile-time indices only.
__device__ __forceinline__ void insert10(float s, int id, float bs[K_NN], int bi[K_NN]) {
    bs[0] = s; bi[0] = id;
#pragma unroll
    for (int t = 0; t < K_NN - 1; ++t) {
        if (bs[t] > bs[t + 1]) {
            float a = bs[t]; bs[t] = bs[t + 1]; bs[t + 1] = a;
            int   b = bi[t]; bi[t] = bi[t + 1]; bi[t + 1] = b;
        }
    }
}

__global__ __launch_bounds__(256, 2) void pair_kernel(
        const float* __restrict__ points,   // [M][N][6]
        const float* __restrict__ estT,     // [M][4][4]
        const float* __restrict__ planeT,   // [4][4]
        float* __restrict__ pair_sd) {      // [M][NSLOT][N]
    __shared__ float4 sref[N_PTS + PAD];            // 48.3 KiB: (x,y,z,|p|^2/2)
    __shared__ unsigned short cand[256 * CSTR];     // 21 KiB; reused for merge

    const int pidx  = blockIdx.x;           // 0..11
    const int q     = pidx / NSLOT;
    const int rs    = pidx % NSLOT;
    const int r     = rs + (rs >= q ? 1 : 0);
    const int tid   = threadIdx.x;
    const int seg   = tid >> 6;             // wave id = segment
    const int qlane = tid & 63;

    float Tq[3][4], Tr[3][4];
    make_T(estT + q * 16, planeT, Tq);
    make_T(estT + r * 16, planeT, Tr);

    // Stage transformed ref points + half-squared-norm. Pad region gets a huge
    // w so its s is ~-1e30 (never pushed even if ever evaluated).
    for (int j = tid; j < N_PTS + PAD; j += 256) {
        if (j < N_PTS) {
            const float* p = points + (size_t)(r * N_PTS + j) * 6;
            float2 xy = *(const float2*)p;
            float  z  = p[2];
            float px = Tr[0][0] * xy.x + Tr[0][1] * xy.y + Tr[0][2] * z + Tr[0][3];
            float py = Tr[1][0] * xy.x + Tr[1][1] * xy.y + Tr[1][2] * z + Tr[1][3];
            float pz = Tr[2][0] * xy.x + Tr[2][1] * xy.y + Tr[2][2] * z + Tr[2][3];
            float w  = 0.5f * (px * px + py * py + pz * pz);
            sref[j] = make_float4(px, py, pz, w);
        } else {
            sref[j] = make_float4(0.f, 0.f, 0.f, 1e30f);
        }
    }
    __syncthreads();

    const int nq = blockIdx.y * QPB + qlane;
    const float* qp = points + (size_t)(q * N_PTS + nq) * 6;
    float2 qxy = *(const float2*)qp;
    float  qzz = qp[2];
    const float qx = Tq[0][0] * qxy.x + Tq[0][1] * qxy.y + Tq[0][2] * qzz + Tq[0][3];
    const float qy = Tq[1][0] * qxy.x + Tq[1][1] * qxy.y + Tq[1][2] * qzz + Tq[1][3];
    const float qz = Tq[2][0] * qxy.x + Tq[2][1] * qxy.y + Tq[2][2] * qzz + Tq[2][3];
    const float qq = qx * qx + qy * qy + qz * qz;   // sq = qq - 2s

    float bs[K_NN]; int bi[K_NN];
#pragma unroll
    for (int i = 0; i < K_NN; ++i) { bs[i] = -3.4e38f; bi[i] = 0; }
    int c = 0;
    const int cbase = tid * CSTR;

    // Branch-free scan with 2-deep register prefetch. Per point: 3 FMA + cmp +
    // predicated u16 push (stale threshold = conservative-correct). Drains are
    // rare (trigger c>23); drain recomputes exact s from sref by index.
    const int j0 = seg * SEGN;
    float4 pA[8], pB[8];
#pragma unroll
    for (int u = 0; u < 8; ++u) pA[u] = sref[j0 + u];

    for (int jb = 0; jb < SEGN; jb += 16) {
        if (__any(c > B_CAND - 17)) {       // room for +16 pushes this iter
            for (int i = 0; i < c; ++i) {   // exec-masked per-lane loop
                int id = cand[cbase + i];
                float4 p = sref[id];
                float s = fmaf(p.x, qx, fmaf(p.y, qy, fmaf(p.z, qz, -p.w)));
                if (s > bs[0]) insert10(s, id, bs, bi);
            }
            c = 0;
        }
        const int jj = j0 + jb;
#pragma unroll
        for (int u = 0; u < 8; ++u) pB[u] = sref[jj + 8 + u];
#pragma unroll
        for (int u = 0; u < 8; ++u) {
            float s = fmaf(pA[u].x, qx, fmaf(pA[u].y, qy, fmaf(pA[u].z, qz, -pA[u].w)));
            if (s > bs[0]) { cand[cbase + c] = (unsigned short)(jj + u); ++c; }
        }
#pragma unroll
        for (int u = 0; u < 8; ++u) pA[u] = sref[jj + 16 + u];   // pad covers tail
#pragma unroll
        for (int u = 0; u < 8; ++u) {
            float s = fmaf(pB[u].x, qx, fmaf(pB[u].y, qy, fmaf(pB[u].z, qz, -pB[u].w)));
            if (s > bs[0]) { cand[cbase + c] = (unsigned short)(jj + 8 + u); ++c; }
        }
    }
    // Final drain.
    for (int i = 0; i < c; ++i) {
        int id = cand[cbase + i];
        float4 p = sref[id];
        float s = fmaf(p.x, qx, fmaf(p.y, qy, fmaf(p.z, qz, -p.w)));
        if (s > bs[0]) insert10(s, id, bs, bi);
    }

    // Cascade merge via u16 ids (s recomputed exactly from sref):
    // w2,w3 publish; w0<-w2, w1<-w3; w1 publishes; w0<-w1.
    __syncthreads();
    if (seg >= 2) {
#pragma unroll
        for (int i = 0; i < K_NN; ++i) cand[cbase + i] = (unsigned short)bi[i];
    }
    __syncthreads();
    if (seg < 2) {
        const int src = (tid + 128) * CSTR;
#pragma unroll
        for (int i = 0; i < K_NN; ++i) {
            int id = cand[src + i];
            float4 p = sref[id];
            float s = fmaf(p.x, qx, fmaf(p.y, qy, fmaf(p.z, qz, -p.w)));
            if (s > bs[0]) insert10(s, id, bs, bi);
        }
    }
    __syncthreads();
    if (seg == 1) {
#pragma unroll
        for (int i = 0; i < K_NN; ++i) cand[cbase + i] = (unsigned short)bi[i];
    }
    __syncthreads();
    if (seg == 0) {
        const int src = (64 + qlane) * CSTR;
#pragma unroll
        for (int i = 0; i < K_NN; ++i) {
            int id = cand[src + i];
            float4 p = sref[id];
            float s = fmaf(p.x, qx, fmaf(p.y, qy, fmaf(p.z, qz, -p.w)));
            if (s > bs[0]) insert10(s, id, bs, bi);
        }

        // Inside/outside vote (unnormalized grad: sign-preserving).
        int votes = 0;
#pragma unroll
        for (int i = 0; i < K_NN; ++i) {
            int id = bi[i];
            float4 p = sref[id];
            float gx = p.x - qx, gy = p.y - qy, gz = p.z - qz;
            const float* np_ = points + (size_t)(r * N_PTS + id) * 6 + 3;
            votes += (np_[0] * gx + np_[1] * gy + np_[2] * gz > 0.0f) ? 1 : 0;
        }

        float sq = fmaxf(fmaf(-2.0f, bs[K_NN - 1], qq), 0.0f);
        float d0 = sqrtf(sq);
        float sd = (votes > 8) ? -d0 : d0;
        pair_sd[((size_t)q * NSLOT + rs) * N_PTS + nq] = sd;
    }
}

__global__ __launch_bounds__(256) void reduce_kernel(
        const float* __restrict__ points,
        const float* __restrict__ estT,
        const float* __restrict__ planeT,
        const float* __restrict__ pair_sd,
        float* __restrict__ out) {
    int i = blockIdx.x * blockDim.x + threadIdx.x;
    if (i >= M_OBJ * N_PTS) return;
    int m = i / N_PTS, n = i % N_PTS;

    float T[3][4];
    make_T(estT + m * 16, planeT, T);
    const float* p = points + (size_t)i * 6;
    float zpl = T[2][0] * p[0] + T[2][1] * p[1] + T[2][2] * p[2] + T[2][3];

    float sd = zpl;
#pragma unroll
    for (int rs = 0; rs < NSLOT; ++rs)
        sd = fminf(sd, pair_sd[((size_t)m * NSLOT + rs) * N_PTS + n]);

    out[i] = sd;
    out[M_OBJ * N_PTS + i] = (sd < -0.01f) ? 1.0f : 0.0f;
}

extern "C" void kernel_launch(void* const* d_in, const int* in_sizes, int n_in,
                              void* d_out, int out_size, void* d_ws, size_t ws_size,
                              hipStream_t stream) {
    const float* points = (const float*)d_in[0];   // [4][3072][6]
    const float* estT   = (const float*)d_in[1];   // [4][4][4]
    const float* planeT = (const float*)d_in[2];   // [4][4]

    float* pair_sd = (float*)d_ws;                 // [4][3][3072]

    dim3 gridB(M_OBJ * NSLOT, N_PTS / QPB);        // 12 x 48 = 576 blocks
    pair_kernel<<<gridB, 256, 0, stream>>>(points, estT, planeT, pair_sd);

    int total = M_OBJ * N_PTS;
    reduce_kernel<<<(total + 255) / 256, 256, 0, stream>>>(points, estT, planeT,
                                                           pair_sd, (float*)d_out);
}

// Round 7
// 139.452 us; speedup vs baseline: 1.4054x; 1.4054x over previous
//
#include <hip/hip_runtime.h>
#include <math.h>

#define M_OBJ 4
#define N_PTS 3072
#define K_NN  10
#define NSLOT (M_OBJ - 1)
#define QPB   64            // queries per block (one per lane)
#define SEG   4             // reference segments (one per wave)
#define SEGN  (N_PTS / SEG) // 768 points per segment (= 12 chunks of 64)
#define MSTR  10            // merge-buffer u16 entries per slot

// T = inv(plane_T) @ est_T (3x4). plane_T is orthonormal-rigid: inv = [R^T|-R^T t].
__device__ inline void make_T(const float* __restrict__ E,
                              const float* __restrict__ P,
                              float T[3][4]) {
    float Pi[3][4];
#pragma unroll
    for (int i = 0; i < 3; ++i) {
#pragma unroll
        for (int j = 0; j < 3; ++j) Pi[i][j] = P[j * 4 + i];
        Pi[i][3] = -(P[0 * 4 + i] * P[3] + P[1 * 4 + i] * P[7] + P[2 * 4 + i] * P[11]);
    }
#pragma unroll
    for (int i = 0; i < 3; ++i) {
#pragma unroll
        for (int j = 0; j < 4; ++j) {
            float acc = (j == 3) ? Pi[i][3] : 0.0f;
#pragma unroll
            for (int kk = 0; kk < 3; ++kk) acc += Pi[i][kk] * E[kk * 4 + j];
            T[i][j] = acc;
        }
    }
}

// bs[] ASCENDING in s (s = p.q - |p|^2/2; larger s == nearer).
// bs[0] = 10th-best (threshold), bs[9] = nearest. Compile-time indices only.
// Strict compares keep first-inserted (lower index) ahead on ties == jnp.top_k.
__device__ __forceinline__ void insert10(float s, int id, float bs[K_NN], int bi[K_NN]) {
    bs[0] = s; bi[0] = id;
#pragma unroll
    for (int t = 0; t < K_NN - 1; ++t) {
        if (bs[t] > bs[t + 1]) {
            float a = bs[t]; bs[t] = bs[t + 1]; bs[t + 1] = a;
            int   b = bi[t]; bi[t] = bi[t + 1]; bi[t + 1] = b;
        }
    }
}

__device__ __forceinline__ float score(const float4 p, float qx, float qy, float qz) {
    return fmaf(p.x, qx, fmaf(p.y, qy, fmaf(p.z, qz, -p.w)));
}

__global__ __launch_bounds__(256, 3) void pair_kernel(
        const float* __restrict__ points,   // [M][N][6]
        const float* __restrict__ estT,     // [M][4][4]
        const float* __restrict__ planeT,   // [4][4]
        float* __restrict__ pair_sd) {      // [M][NSLOT][N]
    __shared__ float4 sref[N_PTS];                  // 49152 B: (x,y,z,|p|^2/2)
    __shared__ unsigned short mbuf[128 * MSTR];     // 2560 B merge buffer
    // total 51712 B (+driver pad) -> 3 blocks/CU, all 576 blocks resident

    const int pidx  = blockIdx.x;           // 0..11
    const int q     = pidx / NSLOT;
    const int rs    = pidx % NSLOT;
    const int r     = rs + (rs >= q ? 1 : 0);
    const int tid   = threadIdx.x;
    const int seg   = tid >> 6;             // wave id = segment
    const int qlane = tid & 63;

    float Tq[3][4], Tr[3][4];
    make_T(estT + q * 16, planeT, Tq);
    make_T(estT + r * 16, planeT, Tr);

    // Stage transformed ref points + half-squared-norm.
    for (int j = tid; j < N_PTS; j += 256) {
        const float* p = points + (size_t)(r * N_PTS + j) * 6;
        float2 xy = *(const float2*)p;
        float  z  = p[2];
        float px = Tr[0][0] * xy.x + Tr[0][1] * xy.y + Tr[0][2] * z + Tr[0][3];
        float py = Tr[1][0] * xy.x + Tr[1][1] * xy.y + Tr[1][2] * z + Tr[1][3];
        float pz = Tr[2][0] * xy.x + Tr[2][1] * xy.y + Tr[2][2] * z + Tr[2][3];
        float w  = 0.5f * (px * px + py * py + pz * pz);
        sref[j] = make_float4(px, py, pz, w);
    }
    __syncthreads();

    const int nq = blockIdx.y * QPB + qlane;
    const float* qp = points + (size_t)(q * N_PTS + nq) * 6;
    float2 qxy = *(const float2*)qp;
    float  qzz = qp[2];
    const float qx = Tq[0][0] * qxy.x + Tq[0][1] * qxy.y + Tq[0][2] * qzz + Tq[0][3];
    const float qy = Tq[1][0] * qxy.x + Tq[1][1] * qxy.y + Tq[1][2] * qzz + Tq[1][3];
    const float qz = Tq[2][0] * qxy.x + Tq[2][1] * qxy.y + Tq[2][2] * qzz + Tq[2][3];
    const float qq = qx * qx + qy * qy + qz * qz;   // sq = qq - 2s

    float bs[K_NN]; int bi[K_NN];
#pragma unroll
    for (int i = 0; i < K_NN; ++i) { bs[i] = -3.4e38f; bi[i] = 0; }

    const int j0 = seg * SEGN;

    // Warm start: unconditionally insert the segment's first 10 points so the
    // threshold bs[0] is live from the start.
#pragma unroll
    for (int i = 0; i < K_NN; ++i)
        insert10(score(sref[j0 + i], qx, qy, qz), j0 + i, bs, bi);

    // 12 chunks of 64 points. Per point: 3 FMA + cmp + sel + or — NO branches,
    // NO LDS writes. Pass-bits accumulate in two u32 registers; the rare path
    // (bit processing) runs once per chunk, cost proportional to candidates.
    for (int c = 0; c < SEGN / 64; ++c) {
        const int jj = j0 + c * 64;
        const float bs0 = bs[0];            // stale within chunk = conservative
        unsigned w0 = 0u, w1 = 0u;
#pragma unroll
        for (int b = 0; b < 32; ++b)
            w0 |= (score(sref[jj + b], qx, qy, qz) > bs0) ? (1u << b) : 0u;
#pragma unroll
        for (int b = 0; b < 32; ++b)
            w1 |= (score(sref[jj + 32 + b], qx, qy, qz) > bs0) ? (1u << b) : 0u;
        if (c == 0) w0 &= ~1023u;           // warm-start points already inserted

        if (__any((w0 | w1) != 0u)) {
            while (__any(w0 != 0u)) {
                if (w0) {
                    const int b = __builtin_ctz(w0); w0 &= w0 - 1u;
                    const int id = jj + b;
                    const float s = score(sref[id], qx, qy, qz);
                    if (s > bs[0]) insert10(s, id, bs, bi);
                }
            }
            while (__any(w1 != 0u)) {
                if (w1) {
                    const int b = __builtin_ctz(w1); w1 &= w1 - 1u;
                    const int id = jj + 32 + b;
                    const float s = score(sref[id], qx, qy, qz);
                    if (s > bs[0]) insert10(s, id, bs, bi);
                }
            }
        }
    }

    // Cascade merge via u16 ids (s recomputed exactly from sref — fma chain is
    // deterministic): w2,w3 publish; w0<-w2, w1<-w3; w1 publishes; w0<-w1.
    __syncthreads();
    if (seg >= 2) {
        const int slot = tid - 128;         // 0..127
#pragma unroll
        for (int i = 0; i < K_NN; ++i) mbuf[slot * MSTR + i] = (unsigned short)bi[i];
    }
    __syncthreads();
    if (seg < 2) {
        const int src = (seg * 64 + qlane) * MSTR;  // w0<-slots 0..63 (w2), w1<-64..127 (w3)
#pragma unroll
        for (int i = 0; i < K_NN; ++i) {
            const int id = mbuf[src + i];
            const float s = score(sref[id], qx, qy, qz);
            if (s > bs[0]) insert10(s, id, bs, bi);
        }
    }
    __syncthreads();
    if (seg == 1) {
#pragma unroll
        for (int i = 0; i < K_NN; ++i) mbuf[qlane * MSTR + i] = (unsigned short)bi[i];
    }
    __syncthreads();
    if (seg == 0) {
        const int src = qlane * MSTR;
#pragma unroll
        for (int i = 0; i < K_NN; ++i) {
            const int id = mbuf[src + i];
            const float s = score(sref[id], qx, qy, qz);
            if (s > bs[0]) insert10(s, id, bs, bi);
        }

        // Inside/outside vote (unnormalized grad: sign-preserving).
        int votes = 0;
#pragma unroll
        for (int i = 0; i < K_NN; ++i) {
            const int id = bi[i];
            float4 p = sref[id];
            float gx = p.x - qx, gy = p.y - qy, gz = p.z - qz;
            const float* np_ = points + (size_t)(r * N_PTS + id) * 6 + 3;
            votes += (np_[0] * gx + np_[1] * gy + np_[2] * gz > 0.0f) ? 1 : 0;
        }

        float sq = fmaxf(fmaf(-2.0f, bs[K_NN - 1], qq), 0.0f);
        float d0 = sqrtf(sq);
        float sd = (votes > 8) ? -d0 : d0;
        pair_sd[((size_t)q * NSLOT + rs) * N_PTS + nq] = sd;
    }
}

__global__ __launch_bounds__(256) void reduce_kernel(
        const float* __restrict__ points,
        const float* __restrict__ estT,
        const float* __restrict__ planeT,
        const float* __restrict__ pair_sd,
        float* __restrict__ out) {
    int i = blockIdx.x * blockDim.x + threadIdx.x;
    if (i >= M_OBJ * N_PTS) return;
    int m = i / N_PTS, n = i % N_PTS;

    float T[3][4];
    make_T(estT + m * 16, planeT, T);
    const float* p = points + (size_t)i * 6;
    float zpl = T[2][0] * p[0] + T[2][1] * p[1] + T[2][2] * p[2] + T[2][3];

    float sd = zpl;
#pragma unroll
    for (int rs = 0; rs < NSLOT; ++rs)
        sd = fminf(sd, pair_sd[((size_t)m * NSLOT + rs) * N_PTS + n]);

    out[i] = sd;
    out[M_OBJ * N_PTS + i] = (sd < -0.01f) ? 1.0f : 0.0f;
}

extern "C" void kernel_launch(void* const* d_in, const int* in_sizes, int n_in,
                              void* d_out, int out_size, void* d_ws, size_t ws_size,
                              hipStream_t stream) {
    const float* points = (const float*)d_in[0];   // [4][3072][6]
    const float* estT   = (const float*)d_in[1];   // [4][4][4]
    const float* planeT = (const float*)d_in[2];   // [4][4]

    float* pair_sd = (float*)d_ws;                 // [4][3][3072]

    dim3 gridB(M_OBJ * NSLOT, N_PTS / QPB);        // 12 x 48 = 576 blocks
    pair_kernel<<<gridB, 256, 0, stream>>>(points, estT, planeT, pair_sd);

    int total = M_OBJ * N_PTS;
    reduce_kernel<<<(total + 255) / 256, 256, 0, stream>>>(points, estT, planeT,
                                                           pair_sd, (float*)d_out);
}

// Round 8
// 128.151 us; speedup vs baseline: 1.5293x; 1.0882x over previous
//
#include <hip/hip_runtime.h>
#include <math.h>

#define M_OBJ 4
#define N_PTS 3072
#define K_NN  10
#define NSLOT (M_OBJ - 1)
#define QPB   64            // queries per block (one per lane)
#define SEG   4             // reference segments (one per wave)
#define SEGN  (N_PTS / SEG) // 768 points per segment (= 12 chunks of 64)
#define NCHUNK (SEGN / 64)  // 12
#define WSTRIDE 16          // warm-start stride (divides 64 -> constant mask)
#define NWARM (SEGN / WSTRIDE) // 48 warm points

// T = inv(plane_T) @ est_T (3x4). plane_T is orthonormal-rigid: inv = [R^T|-R^T t].
__device__ inline void make_T(const float* __restrict__ E,
                              const float* __restrict__ P,
                              float T[3][4]) {
    float Pi[3][4];
#pragma unroll
    for (int i = 0; i < 3; ++i) {
#pragma unroll
        for (int j = 0; j < 3; ++j) Pi[i][j] = P[j * 4 + i];
        Pi[i][3] = -(P[0 * 4 + i] * P[3] + P[1 * 4 + i] * P[7] + P[2 * 4 + i] * P[11]);
    }
#pragma unroll
    for (int i = 0; i < 3; ++i) {
#pragma unroll
        for (int j = 0; j < 4; ++j) {
            float acc = (j == 3) ? Pi[i][3] : 0.0f;
#pragma unroll
            for (int kk = 0; kk < 3; ++kk) acc += Pi[i][kk] * E[kk * 4 + j];
            T[i][j] = acc;
        }
    }
}

// "Insert v into ascending bs[0..9], drop old min" via the med3 identity:
// r_i = med3(v, b_i, b_{i+1}) for i<9, r_9 = max(v, b_9).
// Branchless, 10 independent v_med3_f32 (1-deep), idempotent when v <= bs[0].
__device__ __forceinline__ void insertv(float v, float bs[K_NN]) {
#pragma unroll
    for (int i = 0; i < K_NN - 1; ++i)
        bs[i] = __builtin_amdgcn_fmed3f(v, bs[i], bs[i + 1]);
    bs[K_NN - 1] = fmaxf(v, bs[K_NN - 1]);
}

__global__ __launch_bounds__(256, 3) void pair_kernel(
        const float* __restrict__ points,   // [M][N][6]
        const float* __restrict__ estT,     // [M][4][4]
        const float* __restrict__ planeT,   // [4][4]
        float* __restrict__ pair_sd) {      // [M][NSLOT][N]
    __shared__ float4 sref[N_PTS];          // 49152 B: (x,y,z,|p|^2/2)
    __shared__ float  mbuf[128 * K_NN];     // 5120 B merge buffer
    // ~54 KiB total -> 3 blocks/CU, all 576 blocks resident

    const int pidx  = blockIdx.x;           // 0..11
    const int q     = pidx / NSLOT;
    const int rs    = pidx % NSLOT;
    const int r     = rs + (rs >= q ? 1 : 0);
    const int tid   = threadIdx.x;
    const int seg   = tid >> 6;             // wave id = segment
    const int qlane = tid & 63;

    float Tq[3][4], Tr[3][4];
    make_T(estT + q * 16, planeT, Tq);
    make_T(estT + r * 16, planeT, Tr);

    // Stage transformed ref points + half-squared-norm.
    for (int j = tid; j < N_PTS; j += 256) {
        const float* p = points + (size_t)(r * N_PTS + j) * 6;
        float2 xy = *(const float2*)p;
        float  z  = p[2];
        float px = Tr[0][0] * xy.x + Tr[0][1] * xy.y + Tr[0][2] * z + Tr[0][3];
        float py = Tr[1][0] * xy.x + Tr[1][1] * xy.y + Tr[1][2] * z + Tr[1][3];
        float pz = Tr[2][0] * xy.x + Tr[2][1] * xy.y + Tr[2][2] * z + Tr[2][3];
        float w  = 0.5f * (px * px + py * py + pz * pz);
        sref[j] = make_float4(px, py, pz, w);
    }
    __syncthreads();

    const int nq = blockIdx.y * QPB + qlane;
    const float* qp = points + (size_t)(q * N_PTS + nq) * 6;
    float2 qxy = *(const float2*)qp;
    float  qzz = qp[2];
    const float qx = Tq[0][0] * qxy.x + Tq[0][1] * qxy.y + Tq[0][2] * qzz + Tq[0][3];
    const float qy = Tq[1][0] * qxy.x + Tq[1][1] * qxy.y + Tq[1][2] * qzz + Tq[1][3];
    const float qz = Tq[2][0] * qxy.x + Tq[2][1] * qxy.y + Tq[2][2] * qzz + Tq[2][3];
    const float qq = qx * qx + qy * qy + qz * qz;   // sq = qq - 2s

    const float* nrm_base = points + (size_t)r * N_PTS * 6 + 3;

    // Score a candidate and pack its inside/outside vote into mantissa bit 0.
    // (<=1 ulp perturbation of s; rank gaps ~1% >> 1 ulp. Vote bit rides
    // through all merges for free; no index tracking anywhere.)
    auto cand_packed = [&](int id) -> float {
        float4 p = sref[id];
        float s = fmaf(p.x, qx, fmaf(p.y, qy, fmaf(p.z, qz, -p.w)));
        const float* nb = nrm_base + (size_t)id * 6;
        float gx = p.x - qx, gy = p.y - qy, gz = p.z - qz;
        float dv = fmaf(nb[0], gx, fmaf(nb[1], gy, nb[2] * gz));
        unsigned su = (__float_as_uint(s) & ~1u) | (dv > 0.0f ? 1u : 0u);
        return __uint_as_float(su);
    };

    float bs[K_NN];
#pragma unroll
    for (int i = 0; i < K_NN; ++i) bs[i] = -3.4e38f;

    const int j0 = seg * SEGN;

    // Warm start: 48 strided points (every 16th) -> threshold ~rank-157
    // instead of rank-698 from a contiguous-10 warm start.
#pragma unroll 4
    for (int t = 0; t < NWARM; ++t)
        insertv(cand_packed(j0 + t * WSTRIDE), bs);

    // 12 chunks of 64. Scan: 3 FMA + cmp + sel + or per point, no branches.
    // Walk: pass-bits processed with unconditional (idempotent) med3 inserts.
    for (int c = 0; c < NCHUNK; ++c) {
        const int jj = j0 + c * 64;
        // gate = bs[0] with bit0 cleared: strictly conservative vs packed bits
        const float gate = __uint_as_float(__float_as_uint(bs[0]) & ~1u);
        unsigned w0 = 0u, w1 = 0u;
#pragma unroll
        for (int b = 0; b < 32; ++b) {
            float4 p = sref[jj + b];
            float s = fmaf(p.x, qx, fmaf(p.y, qy, fmaf(p.z, qz, -p.w)));
            w0 |= (s > gate) ? (1u << b) : 0u;
        }
#pragma unroll
        for (int b = 0; b < 32; ++b) {
            float4 p = sref[jj + 32 + b];
            float s = fmaf(p.x, qx, fmaf(p.y, qy, fmaf(p.z, qz, -p.w)));
            w1 |= (s > gate) ? (1u << b) : 0u;
        }
        // warm points (bit positions 0,16 per half) already inserted
        w0 &= ~0x00010001u;
        w1 &= ~0x00010001u;

        // Two independent walks interleaved for ILP.
        while (__any((w0 | w1) != 0u)) {
            if (w0) {
                const int b = __builtin_ctz(w0); w0 &= w0 - 1u;
                insertv(cand_packed(jj + b), bs);
            }
            if (w1) {
                const int b = __builtin_ctz(w1); w1 &= w1 - 1u;
                insertv(cand_packed(jj + 32 + b), bs);
            }
        }
    }

    // Cascade merge of packed values (vote bits ride along, no re-scoring):
    // w2,w3 publish; w0<-w2, w1<-w3; w1 publishes; w0<-w1.
    __syncthreads();
    if (seg >= 2) {
        const int slot = tid - 128;         // 0..127
#pragma unroll
        for (int i = 0; i < K_NN; ++i) mbuf[slot * K_NN + i] = bs[i];
    }
    __syncthreads();
    if (seg < 2) {
        const int src = (seg * 64 + qlane) * K_NN;
#pragma unroll
        for (int i = 0; i < K_NN; ++i) insertv(mbuf[src + i], bs);
    }
    __syncthreads();
    if (seg == 1) {
#pragma unroll
        for (int i = 0; i < K_NN; ++i) mbuf[qlane * K_NN + i] = bs[i];
    }
    __syncthreads();
    if (seg == 0) {
        const int src = qlane * K_NN;
#pragma unroll
        for (int i = 0; i < K_NN; ++i) insertv(mbuf[src + i], bs);

        int votes = 0;
#pragma unroll
        for (int i = 0; i < K_NN; ++i) votes += (__float_as_uint(bs[i]) & 1u);

        const float s1 = __uint_as_float(__float_as_uint(bs[K_NN - 1]) & ~1u);
        float sq = fmaxf(fmaf(-2.0f, s1, qq), 0.0f);
        float d0 = sqrtf(sq);
        float sd = (votes > 8) ? -d0 : d0;
        pair_sd[((size_t)q * NSLOT + rs) * N_PTS + nq] = sd;
    }
}

__global__ __launch_bounds__(256) void reduce_kernel(
        const float* __restrict__ points,
        const float* __restrict__ estT,
        const float* __restrict__ planeT,
        const float* __restrict__ pair_sd,
        float* __restrict__ out) {
    int i = blockIdx.x * blockDim.x + threadIdx.x;
    if (i >= M_OBJ * N_PTS) return;
    int m = i / N_PTS, n = i % N_PTS;

    float T[3][4];
    make_T(estT + m * 16, planeT, T);
    const float* p = points + (size_t)i * 6;
    float zpl = T[2][0] * p[0] + T[2][1] * p[1] + T[2][2] * p[2] + T[2][3];

    float sd = zpl;
#pragma unroll
    for (int rs = 0; rs < NSLOT; ++rs)
        sd = fminf(sd, pair_sd[((size_t)m * NSLOT + rs) * N_PTS + n]);

    out[i] = sd;
    out[M_OBJ * N_PTS + i] = (sd < -0.01f) ? 1.0f : 0.0f;
}

extern "C" void kernel_launch(void* const* d_in, const int* in_sizes, int n_in,
                              void* d_out, int out_size, void* d_ws, size_t ws_size,
                              hipStream_t stream) {
    const float* points = (const float*)d_in[0];   // [4][3072][6]
    const float* estT   = (const float*)d_in[1];   // [4][4][4]
    const float* planeT = (const float*)d_in[2];   // [4][4]

    float* pair_sd = (float*)d_ws;                 // [4][3][3072]

    dim3 gridB(M_OBJ * NSLOT, N_PTS / QPB);        // 12 x 48 = 576 blocks
    pair_kernel<<<gridB, 256, 0, stream>>>(points, estT, planeT, pair_sd);

    int total = M_OBJ * N_PTS;
    reduce_kernel<<<(total + 255) / 256, 256, 0, stream>>>(points, estT, planeT,
                                                           pair_sd, (float*)d_out);
}

// Round 9
// 119.739 us; speedup vs baseline: 1.6367x; 1.0703x over previous
//
#include <hip/hip_runtime.h>
#include <math.h>

#define M_OBJ 4
#define N_PTS 3072
#define K_NN  10
#define NSLOT (M_OBJ - 1)
#define QPB   64            // queries per block (one per lane)
#define SEG   4             // reference segments (one per wave)
#define SEGN  (N_PTS / SEG) // 768 points per segment (= 12 chunks of 64)
#define NCHUNK (SEGN / 64)  // 12
#define WSTRIDE 16          // warm-start stride (divides 64 -> constant mask)
#define NWARM (SEGN / WSTRIDE) // 48 warm points
#define IDBITS 12
#define IDMASK ((1u << IDBITS) - 1u)   // 3072 ids fit in 12 bits

// T = inv(plane_T) @ est_T (3x4). plane_T is orthonormal-rigid: inv = [R^T|-R^T t].
__device__ inline void make_T(const float* __restrict__ E,
                              const float* __restrict__ P,
                              float T[3][4]) {
    float Pi[3][4];
#pragma unroll
    for (int i = 0; i < 3; ++i) {
#pragma unroll
        for (int j = 0; j < 3; ++j) Pi[i][j] = P[j * 4 + i];
        Pi[i][3] = -(P[0 * 4 + i] * P[3] + P[1 * 4 + i] * P[7] + P[2 * 4 + i] * P[11]);
    }
#pragma unroll
    for (int i = 0; i < 3; ++i) {
#pragma unroll
        for (int j = 0; j < 4; ++j) {
            float acc = (j == 3) ? Pi[i][3] : 0.0f;
#pragma unroll
            for (int kk = 0; kk < 3; ++kk) acc += Pi[i][kk] * E[kk * 4 + j];
            T[i][j] = acc;
        }
    }
}

// "Insert v into ascending bs[0..9], drop old min" via the med3 identity.
// Branchless, 10 near-parallel v_med3_f32; no-op when v <= bs[0].
__device__ __forceinline__ void insertv(float v, float bs[K_NN]) {
#pragma unroll
    for (int i = 0; i < K_NN - 1; ++i)
        bs[i] = __builtin_amdgcn_fmed3f(v, bs[i], bs[i + 1]);
    bs[K_NN - 1] = fmaxf(v, bs[K_NN - 1]);
}

__device__ __forceinline__ float score4(const float4 p, float qx, float qy, float qz) {
    return fmaf(p.x, qx, fmaf(p.y, qy, fmaf(p.z, qz, -p.w)));
}

__global__ __launch_bounds__(256, 3) void pair_kernel(
        const float* __restrict__ points,   // [M][N][6]
        const float* __restrict__ estT,     // [M][4][4]
        const float* __restrict__ planeT,   // [4][4]
        float* __restrict__ pair_sd) {      // [M][NSLOT][N]
    __shared__ float4 sref[N_PTS];          // 49152 B: (x,y,z,|p|^2/2)
    __shared__ float  mbuf[128 * K_NN];     // 5120 B merge buffer
    // ~54 KiB total -> 3 blocks/CU

    const int pidx  = blockIdx.x;           // 0..11
    const int q     = pidx / NSLOT;
    const int rs    = pidx % NSLOT;
    const int r     = rs + (rs >= q ? 1 : 0);
    const int tid   = threadIdx.x;
    const int seg   = tid >> 6;             // wave id = segment
    const int qlane = tid & 63;

    float Tq[3][4], Tr[3][4];
    make_T(estT + q * 16, planeT, Tq);
    make_T(estT + r * 16, planeT, Tr);

    // Stage transformed ref points + half-squared-norm.
    for (int j = tid; j < N_PTS; j += 256) {
        const float* p = points + (size_t)(r * N_PTS + j) * 6;
        float2 xy = *(const float2*)p;
        float  z  = p[2];
        float px = Tr[0][0] * xy.x + Tr[0][1] * xy.y + Tr[0][2] * z + Tr[0][3];
        float py = Tr[1][0] * xy.x + Tr[1][1] * xy.y + Tr[1][2] * z + Tr[1][3];
        float pz = Tr[2][0] * xy.x + Tr[2][1] * xy.y + Tr[2][2] * z + Tr[2][3];
        float w  = 0.5f * (px * px + py * py + pz * pz);
        sref[j] = make_float4(px, py, pz, w);
    }
    __syncthreads();

    const int nq = blockIdx.y * QPB + qlane;
    const float* qp = points + (size_t)(q * N_PTS + nq) * 6;
    float2 qxy = *(const float2*)qp;
    float  qzz = qp[2];
    const float qx = Tq[0][0] * qxy.x + Tq[0][1] * qxy.y + Tq[0][2] * qzz + Tq[0][3];
    const float qy = Tq[1][0] * qxy.x + Tq[1][1] * qxy.y + Tq[1][2] * qzz + Tq[1][3];
    const float qz = Tq[2][0] * qxy.x + Tq[2][1] * qxy.y + Tq[2][2] * qzz + Tq[2][3];
    const float qq = qx * qx + qy * qy + qz * qz;   // sq = qq - 2s

    // Candidate = s with the point id packed into the low 12 mantissa bits.
    // <=4096-ulp perturbation; ranking flips only among near-ties (output
    // diff ~1e-3 << tol); final distance is recomputed exactly from the id.
    auto pack = [&](int id) -> float {
        float s = score4(sref[id], qx, qy, qz);
        return __uint_as_float((__float_as_uint(s) & ~IDMASK) | (unsigned)id);
    };

    float bs[K_NN];
#pragma unroll
    for (int i = 0; i < K_NN; ++i) bs[i] = -3.4e38f;

    const int j0 = seg * SEGN;

    // Warm start: 48 strided points -> threshold ~rank-157 before chunk 0.
#pragma unroll 4
    for (int t = 0; t < NWARM; ++t)
        insertv(pack(j0 + t * WSTRIDE), bs);

    // 12 chunks of 64. Scan: 3 FMA + cmp + sel + or per point, no branches,
    // no LDS writes. Walk: id-packed inserts, LDS-only, no compare needed
    // (insertv is a no-op for losers).
    for (int c = 0; c < NCHUNK; ++c) {
        const int jj = j0 + c * 64;
        // Conservative gate: bs[0] minus packing slack (sign-safe, in float).
        const float b0 = bs[0];
        const float gate = fmaf(-fabsf(b0), 1.0e-3f, b0) - 1e-30f;
        unsigned w0 = 0u, w1 = 0u;
#pragma unroll
        for (int b = 0; b < 32; ++b) {
            float s = score4(sref[jj + b], qx, qy, qz);
            w0 |= (s > gate) ? (1u << b) : 0u;
        }
#pragma unroll
        for (int b = 0; b < 32; ++b) {
            float s = score4(sref[jj + 32 + b], qx, qy, qz);
            w1 |= (s > gate) ? (1u << b) : 0u;
        }
        // warm points (bits 0,16 of each half) already inserted; masking also
        // prevents duplicate insertion (insertv does not dedupe).
        w0 &= ~0x00010001u;
        w1 &= ~0x00010001u;

        while (__any((w0 | w1) != 0u)) {
            if (w0) {
                const int b = __builtin_ctz(w0); w0 &= w0 - 1u;
                insertv(pack(jj + b), bs);
            }
            if (w1) {
                const int b = __builtin_ctz(w1); w1 &= w1 - 1u;
                insertv(pack(jj + 32 + b), bs);
            }
        }
    }

    // Cascade merge of packed values (ids ride along; segments are disjoint
    // so no duplicates): w2,w3 publish; w0<-w2, w1<-w3; w1 publishes; w0<-w1.
    __syncthreads();
    if (seg >= 2) {
        const int slot = tid - 128;         // 0..127
#pragma unroll
        for (int i = 0; i < K_NN; ++i) mbuf[slot * K_NN + i] = bs[i];
    }
    __syncthreads();
    if (seg < 2) {
        const int src = (seg * 64 + qlane) * K_NN;
#pragma unroll
        for (int i = 0; i < K_NN; ++i) insertv(mbuf[src + i], bs);
    }
    __syncthreads();
    if (seg == 1) {
#pragma unroll
        for (int i = 0; i < K_NN; ++i) mbuf[qlane * K_NN + i] = bs[i];
    }
    __syncthreads();
    if (seg == 0) {
        const int src = qlane * K_NN;
#pragma unroll
        for (int i = 0; i < K_NN; ++i) insertv(mbuf[src + i], bs);

        // Result-frequency work only: 10 ids -> votes + exact nearest dist.
        const float* nrm_base = points + (size_t)r * N_PTS * 6 + 3;
        int votes = 0;
        float s_best = -3.4e38f;
#pragma unroll
        for (int i = 0; i < K_NN; ++i) {
            const int id = (int)(__float_as_uint(bs[i]) & IDMASK);
            float4 p = sref[id];
            float s = score4(p, qx, qy, qz);
            if (i == K_NN - 1) s_best = s;      // bs[9] = nearest (packed max)
            const float* nb = nrm_base + (size_t)id * 6;
            float gx = p.x - qx, gy = p.y - qy, gz = p.z - qz;
            votes += (fmaf(nb[0], gx, fmaf(nb[1], gy, nb[2] * gz)) > 0.0f) ? 1 : 0;
        }

        float sq = fmaxf(fmaf(-2.0f, s_best, qq), 0.0f);
        float d0 = sqrtf(sq);
        float sd = (votes > 8) ? -d0 : d0;
        pair_sd[((size_t)q * NSLOT + rs) * N_PTS + nq] = sd;
    }
}

__global__ __launch_bounds__(256) void reduce_kernel(
        const float* __restrict__ points,
        const float* __restrict__ estT,
        const float* __restrict__ planeT,
        const float* __restrict__ pair_sd,
        float* __restrict__ out) {
    int i = blockIdx.x * blockDim.x + threadIdx.x;
    if (i >= M_OBJ * N_PTS) return;
    int m = i / N_PTS, n = i % N_PTS;

    float T[3][4];
    make_T(estT + m * 16, planeT, T);
    const float* p = points + (size_t)i * 6;
    float zpl = T[2][0] * p[0] + T[2][1] * p[1] + T[2][2] * p[2] + T[2][3];

    float sd = zpl;
#pragma unroll
    for (int rs = 0; rs < NSLOT; ++rs)
        sd = fminf(sd, pair_sd[((size_t)m * NSLOT + rs) * N_PTS + n]);

    out[i] = sd;
    out[M_OBJ * N_PTS + i] = (sd < -0.01f) ? 1.0f : 0.0f;
}

extern "C" void kernel_launch(void* const* d_in, const int* in_sizes, int n_in,
                              void* d_out, int out_size, void* d_ws, size_t ws_size,
                              hipStream_t stream) {
    const float* points = (const float*)d_in[0];   // [4][3072][6]
    const float* estT   = (const float*)d_in[1];   // [4][4][4]
    const float* planeT = (const float*)d_in[2];   // [4][4]

    float* pair_sd = (float*)d_ws;                 // [4][3][3072]

    dim3 gridB(M_OBJ * NSLOT, N_PTS / QPB);        // 12 x 48 = 576 blocks
    pair_kernel<<<gridB, 256, 0, stream>>>(points, estT, planeT, pair_sd);

    int total = M_OBJ * N_PTS;
    reduce_kernel<<<(total + 255) / 256, 256, 0, stream>>>(points, estT, planeT,
                                                           pair_sd, (float*)d_out);
}